// Round 5
// baseline (71.309 us; speedup 1.0000x reference)
//
#include <hip/hip_runtime.h>
#include <math.h>

// HiPPO-LegS reconstruction: out = sum_{i=1..256} coef[i-1]*sqrt(2i+1)*P_i(x),
// x = 2t/curr_t - 1.
//
// R4 post-mortem: zero-load unrolled Q-recurrence = 4 VALU/degree, issue
// (8cyc/deg/wave) == dep chain (8cyc/deg) at 8 waves/SIMD -> no slack, ~21us.
// R5: convert basis once (O(N^2) pre-kernel), evaluate with Clenshaw:
//   P_n = sum'_{m=n(2)} (2/pi)*eps_m*Lam((n-m)/2)*Lam((n+m)/2) * T_m,
//   Lam(j) = Gamma(j+1/2)/Gamma(j+1)  (exact prefix-product)
//   f = sum_m c_m T_m via  b_k = fma(2x,b1,-b2) + c_k   -> 2 VALU/degree,
// zero in-loop vector memory, c_k on the scalar pipe. Issue floor 3.4us.

#define NDEG 256

// ---- pre-kernel: weighted-Legendre -> Chebyshev coefficients c[0..256] ----
__global__ __launch_bounds__(256) void leg2cheb(
    const float* __restrict__ coef, float* __restrict__ c)
{
    __shared__ float lam[NDEG + 1];   // Lambda(0..256)
    __shared__ float wp[NDEG + 1];    // w'(1..256) = coef[n-1]*sqrt(2n+1)
    __shared__ float scan[256];
    const int tid = threadIdx.x;

    // Lambda(j)/sqrt(pi) = prod_{i=1..j} (i-1/2)/i  via inclusive prefix product
    scan[tid] = (tid == 0) ? 1.0f : (((float)tid - 0.5f) / (float)tid);
    __syncthreads();
    for (int off = 1; off < 256; off <<= 1) {
        float v = (tid >= off) ? scan[tid - off] : 1.0f;
        __syncthreads();
        scan[tid] *= v;   // own slot only -> race-free with the barrier above
        __syncthreads();
    }
    const float SQRTPI = 1.7724538509055160f;
    lam[tid] = SQRTPI * scan[tid];
    if (tid == 255) lam[256] = lam[255] * (255.5f / 256.0f);
    wp[tid + 1] = coef[tid] * sqrtf(2.0f * (float)(tid + 1) + 1.0f);
    __syncthreads();

    // c_m = eps_m*(2/pi) * sum_{n>=max(m,1), n=m mod 2} wp_n*Lam((n-m)/2)*Lam((n+m)/2)
    const int m = tid;
    const float TWOOPI = 0.63661977236758134f;
    float s = 0.0f;
    for (int n = (m == 0 ? 2 : m); n <= NDEG; n += 2)
        s += wp[n] * lam[(n - m) >> 1] * lam[(n + m) >> 1];
    c[m] = s * TWOOPI * ((m == 0) ? 0.5f : 1.0f);
    if (tid == 0)  // single term n=256 for m=256
        c[NDEG] = wp[NDEG] * TWOOPI * lam[0] * lam[NDEG];
}

// ---- main kernel: Clenshaw evaluation, 2 VALU/degree, no in-loop vmem ----
__global__ __launch_bounds__(256, 8) void cheb_eval(
    const float* __restrict__ t,
    const int* __restrict__ curr_t,
    const float* __restrict__ c,
    float* __restrict__ out,
    int n)
{
    const int gid = blockIdx.x * 256 + threadIdx.x;
    if (gid >= n) return;

    const float s = 2.0f / (float)curr_t[0];
    const float x = fmaf(t[gid], s, -1.0f);   // x = 2t/curr_t - 1
    const float U = 2.0f * x;

    float b1 = 0.0f, b2 = 0.0f;
#pragma unroll
    for (int k = NDEG; k >= 1; --k) {
        // b_k = c_k + 2x*b_{k+1} - b_{k+2}:  v_fma (VOP3) + v_add (SGPR src)
        float bn = fmaf(U, b1, -b2) + c[k];
        b2 = b1;
        b1 = bn;
    }
    out[gid] = fmaf(x, b1, -b2) + c[0];
}

extern "C" void kernel_launch(void* const* d_in, const int* in_sizes, int n_in,
                              void* d_out, int out_size, void* d_ws, size_t ws_size,
                              hipStream_t stream)
{
    const float* t      = (const float*)d_in[0];
    const float* coef   = (const float*)d_in[1];
    const int*   curr_t = (const int*)d_in[2];
    float*       out    = (float*)d_out;
    float*       c      = (float*)d_ws;     // 257 floats of scratch

    int n = in_sizes[0];                    // 524288
    leg2cheb<<<1, 256, 0, stream>>>(coef, c);
    int blocks = (n + 255) / 256;           // 2048 blocks -> 8 waves/SIMD
    cheb_eval<<<blocks, 256, 0, stream>>>(t, curr_t, c, out, n);
}

// Round 6
// 64.240 us; speedup vs baseline: 1.1101x; 1.1101x over previous
//
#include <hip/hip_runtime.h>
#include <math.h>

// HiPPO-LegS reconstruction: out = sum_{k=1..256} coef[k-1]*sqrt(2k+1)*P_k(x),
// x = 2t/curr_t - 1.
//
// R6: single kernel, Clenshaw directly on the rescaled Legendre basis:
//   S_{d+1} = 2x*S_d - beta_d*S_{d-1},  beta_d = 4d^2/(4d^2-1) (compile-time)
//   S_0 = 1/2, S_1 = x;  f = sum w'_k S_k, w'_k = coef[k-1]*sqrt(2k+1)*g_k
//   Clenshaw: b_k = w'_k + 2x*b_{k+1} - beta_{k+1}*b_{k+2};  f = x*b1 - (2/3)*b2
// -> 2 VALU/degree (fma(-beta_s, b2, w_v); fma(2x, b1, t)), chain 4cyc/deg,
// issue-bound at 8 waves/SIMD. w' built per block into LDS (no 2nd kernel
// node - R3/R5 showed a dependent node costs ~6-9us), read as broadcast
// ds_read_b128 per 4 degrees, prefetch distance 2. ~9KB unrolled: I$-resident.
// VALU floor: 512 instr/thread * 2cyc * 8 waves/SIMD = 8.2k cyc ~= 3.4us.

#define NDEG 256

// g_i = 2*C(2i,i)/4^i: exact for i<8 (branchless selects), 4-term Stirling
// beyond (rel < 1e-7). Same math as R3/R4 (passed, absmax 0.5).
__device__ __forceinline__ float g_of(int i) {
    const float fi = (float)i;
    float r = 2.0f * rsqrtf(3.14159265358979f * fi);
    float inv = 1.0f / fi;
    float corr = 1.0f + inv * (-0.125f + inv * (0.0078125f + inv * 0.0048828125f));
    float g = r * corr;
    g = (i == 1) ? 1.0f          : g;
    g = (i == 2) ? 0.75f         : g;
    g = (i == 3) ? 0.625f        : g;
    g = (i == 4) ? 0.546875f     : g;
    g = (i == 5) ? 0.4921875f    : g;
    g = (i == 6) ? 0.451171875f  : g;
    g = (i == 7) ? 0.4189453125f : g;
    return g;
}

// One Clenshaw degree K (descending): b_K = w + 2x*b1 - beta_{K+1}*b2.
template <int K>
__device__ __forceinline__ void step(const float U, float& b1, float& b2,
                                     const float w) {
    constexpr double d = (double)(K + 1);
    constexpr float NB = (float)(-(4.0 * d * d) / (4.0 * d * d - 1.0));
    float tt = fmaf(NB, b2, w);   // -beta_{K+1}*b2 + w'_K  (1 sgpr + 2 vgpr)
    float bn = fmaf(U, b1, tt);   // + 2x*b_{K+1}
    b2 = b1;
    b1 = bn;
}

// Chunk J covers degrees 4J+4 .. 4J+1 from one float4 LDS broadcast.
template <int J>
struct Chunk {
    static __device__ __forceinline__ void run(const float U, float& b1,
                                               float& b2,
                                               const float4* __restrict__ w4,
                                               float4 c, float4 cn) {
        float4 c2 = w4[(J >= 2) ? (J - 2) : 0];  // prefetch distance 2
        step<4 * J + 4>(U, b1, b2, c.w);
        step<4 * J + 3>(U, b1, b2, c.z);
        step<4 * J + 2>(U, b1, b2, c.y);
        step<4 * J + 1>(U, b1, b2, c.x);
        Chunk<J - 1>::run(U, b1, b2, w4, cn, c2);
    }
};
template <>
struct Chunk<-1> {
    static __device__ __forceinline__ void run(float, float&, float&,
                                               const float4*, float4, float4) {}
};

__global__ __launch_bounds__(256, 8) void hippo_kernel(
    const float* __restrict__ t,
    const float* __restrict__ coef,
    const int* __restrict__ curr_t,
    float* __restrict__ out,
    int n)
{
    // w'[k] for k=1..256 packed so w4[j] = {w'(4j+1),w'(4j+2),w'(4j+3),w'(4j+4)}
    __shared__ float4 w4[NDEG / 4];
    float* wf = (float*)w4;

    const int tid = threadIdx.x;
    {
        const int k = tid + 1;
        wf[tid] = coef[tid] * sqrtf(2.0f * (float)k + 1.0f) * g_of(k);
    }
    __syncthreads();

    const int gid = blockIdx.x * 256 + tid;
    if (gid >= n) return;

    const float s = 2.0f / (float)curr_t[0];
    const float x = fmaf(t[gid], s, -1.0f);   // x = 2t/curr_t - 1
    const float U = 2.0f * x;

    float b1 = 0.0f, b2 = 0.0f;               // b_258 = b_257 = 0
    Chunk<63>::run(U, b1, b2, w4, w4[63], w4[62]);  // degrees 256..1

    // f = x*b_1 - beta_1*S_0*b_2 = x*b1 - (4/3)*(1/2)*b2
    out[gid] = fmaf(x, b1, -0.66666666666667f * b2);
}

extern "C" void kernel_launch(void* const* d_in, const int* in_sizes, int n_in,
                              void* d_out, int out_size, void* d_ws, size_t ws_size,
                              hipStream_t stream)
{
    const float* t      = (const float*)d_in[0];
    const float* coef   = (const float*)d_in[1];
    const int*   curr_t = (const int*)d_in[2];
    float*       out    = (float*)d_out;

    int n = in_sizes[0];                 // 524288
    int blocks = (n + 255) / 256;        // 2048 blocks -> 8 waves/SIMD
    hippo_kernel<<<blocks, 256, 0, stream>>>(t, coef, curr_t, out, n);
}

// Round 7
// 64.001 us; speedup vs baseline: 1.1142x; 1.0037x over previous
//
#include <hip/hip_runtime.h>
#include <math.h>

// HiPPO-LegS reconstruction: out = sum_{k=1..256} coef[k-1]*sqrt(2k+1)*P_k(x),
// x = 2t/curr_t - 1.
//
// Model (fit over R1-R6): dur_us = ~58.6us harness floor (268MB ws re-poison
// @40.5us + restores + replay overhead) + kernel. R4 landed exactly on its
// 4-op issue floor (6.8us); R6 (2-op Clenshaw) = 5.6us vs ~3.8us floor.
// R7: same Clenshaw math as R6, but plain fully-unrolled loop -- no manual
// prefetch recursion (bounded LDS-read window, ~20 VGPR, no hoist-to-spill),
// steps shaped for VOP2 v_fmac (literal beta inline, zero SGPR moves).
//
//   Clenshaw on rescaled basis S_{d+1} = 2x*S_d - beta_d*S_{d-1}:
//   b_k = w'_k + 2x*b_{k+1} - beta_{k+1}*b_{k+2};  f = x*b_1 - (2/3)*b_2
//   beta_d = 4d^2/(4d^2-1) (compile-time), w'_k = coef[k-1]*sqrt(2k+1)*g_k

#define NDEG 256

// g_i = 2*C(2i,i)/4^i: exact for i<8, 4-term Stirling beyond (rel < 1e-7).
__device__ __forceinline__ float g_of(int i) {
    const float fi = (float)i;
    float r = 2.0f * rsqrtf(3.14159265358979f * fi);
    float inv = 1.0f / fi;
    float corr = 1.0f + inv * (-0.125f + inv * (0.0078125f + inv * 0.0048828125f));
    float g = r * corr;
    g = (i == 1) ? 1.0f          : g;
    g = (i == 2) ? 0.75f         : g;
    g = (i == 3) ? 0.625f        : g;
    g = (i == 4) ? 0.546875f     : g;
    g = (i == 5) ? 0.4921875f    : g;
    g = (i == 6) ? 0.451171875f  : g;
    g = (i == 7) ? 0.4189453125f : g;
    return g;
}

// -beta_{d} as a compile-time-foldable constant.
constexpr float nbeta(int d) {
    double dd = (double)d;
    return (float)(-(4.0 * dd * dd) / (4.0 * dd * dd - 1.0));
}

// One Clenshaw degree: b_K = w + 2x*b1 - beta_{K+1}*b2.
// Shaped so both ops are v_fmac_f32 (VOP2, literal nb inline in src0).
__device__ __forceinline__ void step(const float U, float& b1, float& b2,
                                     const float nb, const float w) {
    float tt = fmaf(nb, b2, w);   // v_fmac: tt(=w) += nb*b2
    float bn = fmaf(U, b1, tt);   // v_fmac: tt += U*b1
    b2 = b1;
    b1 = bn;
}

__global__ __launch_bounds__(256, 8) void hippo_kernel(
    const float* __restrict__ t,
    const float* __restrict__ coef,
    const int* __restrict__ curr_t,
    float* __restrict__ out,
    int n)
{
    // w'[k], k=1..256: w4[j] = {w'(4j+1), w'(4j+2), w'(4j+3), w'(4j+4)}
    __shared__ float4 w4[NDEG / 4];
    float* wf = (float*)w4;

    const int tid = threadIdx.x;
    {
        const int k = tid + 1;
        wf[tid] = coef[tid] * sqrtf(2.0f * (float)k + 1.0f) * g_of(k);
    }
    __syncthreads();

    const int gid = blockIdx.x * 256 + tid;
    const float s = 2.0f / (float)curr_t[0];
    const float x = fmaf(t[gid < n ? gid : 0], s, -1.0f);  // x = 2t/curr_t - 1
    const float U = 2.0f * x;

    float b1 = 0.0f, b2 = 0.0f;   // b_258 = b_257 = 0
#pragma unroll
    for (int j = 63; j >= 0; --j) {
        const float4 c = w4[j];   // broadcast ds_read_b128, scheduler-managed
        step(U, b1, b2, nbeta(4 * j + 5), c.w);  // degree 4j+4
        step(U, b1, b2, nbeta(4 * j + 4), c.z);  // degree 4j+3
        step(U, b1, b2, nbeta(4 * j + 3), c.y);  // degree 4j+2
        step(U, b1, b2, nbeta(4 * j + 2), c.x);  // degree 4j+1
    }

    // f = x*b_1 - beta_1*S_0*b_2 = x*b1 - (4/3)*(1/2)*b2
    if (gid < n)
        out[gid] = fmaf(x, b1, -0.66666666666667f * b2);
}

extern "C" void kernel_launch(void* const* d_in, const int* in_sizes, int n_in,
                              void* d_out, int out_size, void* d_ws, size_t ws_size,
                              hipStream_t stream)
{
    const float* t      = (const float*)d_in[0];
    const float* coef   = (const float*)d_in[1];
    const int*   curr_t = (const int*)d_in[2];
    float*       out    = (float*)d_out;

    int n = in_sizes[0];                 // 524288
    int blocks = (n + 255) / 256;        // 2048 blocks -> 8 waves/SIMD
    hippo_kernel<<<blocks, 256, 0, stream>>>(t, coef, curr_t, out, n);
}